// Round 9
// baseline (96.318 us; speedup 1.0000x reference)
//
#include <hip/hip_runtime.h>
#include <hip/hip_bf16.h>

#define Bdim 2
#define Hdim 16
#define Sdim 2048
#define Ddim 64
#define KVBLK 64
#define NT (Sdim / KVBLK)      // 32
#define WQ 32                  // q-rows per wave
#define NWAVE 4
#define QTILE (WQ * NWAVE)     // 128
#define QSCL (0.125f * 1.44269504088896f)   // 1/sqrt(64) * log2(e), exp2 domain
#define SCALE 0.125f
#define BUFE 8192              // elems per LDS buffer: K 64x64 + V 64x64
#define VOFF 4096              // V offset within buffer

typedef __bf16 bf16x8 __attribute__((ext_vector_type(8)));
typedef float  f32x4  __attribute__((ext_vector_type(4)));
typedef float  f32x16 __attribute__((ext_vector_type(16)));
typedef unsigned u32x4 __attribute__((ext_vector_type(4)));

// ---------------------------------------------------------------------------
// helpers
// ---------------------------------------------------------------------------
__device__ __forceinline__ void gll16(const __bf16* g, __bf16* l) {
  __builtin_amdgcn_global_load_lds(
      (const __attribute__((address_space(1))) void*)g,
      (__attribute__((address_space(3))) void*)l, 16, 0, 0);
}
// hardware pack: two f32 -> dword of 2 bf16 (RNE); nominal: first arg -> low
__device__ __forceinline__ unsigned cvtpk_raw(float lo, float hi) {
  unsigned r;
  asm("v_cvt_pk_bf16_f32 %0, %1, %2" : "=v"(r) : "v"(lo), "v"(hi));
  return r;
}
template <bool SW>
__device__ __forceinline__ unsigned pko(float a, float b) {
  return SW ? cvtpk_raw(b, a) : cvtpk_raw(a, b);
}
__device__ __forceinline__ unsigned cvtpk(float a, float b, bool sw) {
  const float lo = sw ? b : a;
  const float hi = sw ? a : b;
  return cvtpk_raw(lo, hi);
}
// pack all 16 P dwords: pw[ks*4 + {W0,W1,X0,X1}]
template <bool SW>
__device__ __forceinline__ void packAll(const float (&sv0)[16],
                                        const float (&sv1)[16],
                                        unsigned (&pw)[16]) {
#pragma unroll
  for (int ks = 0; ks < 4; ++ks) {
    const int rb = 8 * (ks & 1);
    if (ks < 2) {
      pw[ks * 4 + 0] = pko<SW>(sv0[rb + 0], sv0[rb + 1]);
      pw[ks * 4 + 1] = pko<SW>(sv0[rb + 2], sv0[rb + 3]);
      pw[ks * 4 + 2] = pko<SW>(sv0[rb + 4], sv0[rb + 5]);
      pw[ks * 4 + 3] = pko<SW>(sv0[rb + 6], sv0[rb + 7]);
    } else {
      pw[ks * 4 + 0] = pko<SW>(sv1[rb + 0], sv1[rb + 1]);
      pw[ks * 4 + 1] = pko<SW>(sv1[rb + 2], sv1[rb + 3]);
      pw[ks * 4 + 2] = pko<SW>(sv1[rb + 4], sv1[rb + 5]);
      pw[ks * 4 + 3] = pko<SW>(sv1[rb + 6], sv1[rb + 7]);
    }
  }
}

// ---------------------------------------------------------------------------
// Fused prepass: blocks [0,512) pack mask bits; blocks [512,1536) convert
// K fp32->bf16 (layout-preserving) and V fp32 -> Vt[bh][d][s] bf16.
// ---------------------------------------------------------------------------
__global__ __launch_bounds__(256) void prep_all(
    const void* __restrict__ mask, unsigned long long* __restrict__ packed,
    const float* __restrict__ K, const float* __restrict__ V,
    __bf16* __restrict__ Kb, __bf16* __restrict__ Vt) {
  __shared__ __bf16 tile[64][72];   // +8 pad (used by transpose half only)
  const int t = threadIdx.x;

  if (blockIdx.x < 512) {
    // ---- pack mask (grid-stride over 131072 words, 2048 waves)
    const int nwords = Bdim * Sdim * (Sdim / 64);
    const unsigned* m32 = (const unsigned*)mask;
    const unsigned char* m8 = (const unsigned char*)mask;
    int gid = blockIdx.x * 256 + t;
    int lane = gid & 63;
    int wid = gid >> 6;
    const int nwaves = 512 * 256 / 64;
    bool isBytes = __any(m32[lane] > 1u);   // wave-uniform dtype probe
    for (int w = wid; w < nwords; w += nwaves) {
      int v = isBytes ? (int)m8[(size_t)w * 64 + lane]
                      : (int)m32[(size_t)w * 64 + lane];
      unsigned long long bal = __ballot(v != 0);
      if (lane == 0) packed[w] = bal;
    }
    return;
  }

  const int idx = blockIdx.x - 512;
  const int bh = idx >> 5, st = idx & 31;
  const int r = t >> 2, c0 = (t & 3) << 4;
  {  // K convert, layout-preserving
    const float* ks = K + ((size_t)bh * Sdim + st * 64 + r) * Ddim + c0;
    bf16x8 o0, o1;
#pragma unroll
    for (int j = 0; j < 8; ++j) o0[j] = (__bf16)ks[j];
#pragma unroll
    for (int j = 0; j < 8; ++j) o1[j] = (__bf16)ks[8 + j];
    __bf16* kd = Kb + ((size_t)bh * Sdim + st * 64 + r) * Ddim + c0;
    *(bf16x8*)kd = o0;
    *(bf16x8*)(kd + 8) = o1;
  }
  {  // V -> LDS tile (bf16)
    const float* vs = V + ((size_t)bh * Sdim + st * 64 + r) * Ddim + c0;
#pragma unroll
    for (int j = 0; j < 16; ++j) tile[r][c0 + j] = (__bf16)vs[j];
  }
  __syncthreads();
  {  // transposed write
    const int d = t >> 2, s0 = (t & 3) << 4;
    __bf16 o[16];
#pragma unroll
    for (int j = 0; j < 16; ++j) o[j] = tile[s0 + j][d];
    __bf16* dst = Vt + ((size_t)bh * Ddim + d) * Sdim + st * 64 + s0;
    *(bf16x8*)dst = *(bf16x8*)&o[0];
    *(bf16x8*)(dst + 8) = *(bf16x8*)&o[8];
  }
}

// ---------------------------------------------------------------------------
// Main: swapped-QK^T flash attention, 32x32 MFMA, static-max in-reg softmax.
// 4 waves share K/V tiles; FOUR LDS buffers + x4-unrolled K-loop so every
// buffer offset is a compile-time constant (ds_read = invariant vaddr + imm).
// Single barrier per iteration (writer t+1 vs readers {t, t-1}: >=1 apart mod 4).
// ---------------------------------------------------------------------------
__global__ __launch_bounds__(256, 2) void attn5(
    const float* __restrict__ Q, const __bf16* __restrict__ Kb,
    const __bf16* __restrict__ Vt,
    const unsigned long long* __restrict__ maskP, float* __restrict__ Out) {
  __shared__ alignas(16) __bf16 sm[4 * BUFE];   // 4 x (K 8KB + V 8KB) = 64 KB

  const int tid = threadIdx.x;
  const int lane = tid & 63;
  const int w = tid >> 6;          // 0..3
  const int l31 = lane & 31;
  const int hi = lane >> 5;
  const int rsw = l31 & 7;

  const int bid = blockIdx.x;
  const int bh = bid & 31;            // same-bh blocks share an XCD (bid%8 const)
  const int qt = bid >> 5;
  const int b = bh >> 4;
  const int qrow = qt * QTILE + w * WQ + l31;

  const __bf16* Kbase = Kb + (size_t)bh * Sdim * Ddim;
  const __bf16* Vbase = Vt + (size_t)bh * (size_t)Ddim * Sdim;
  const unsigned long long* mp =
      maskP + ((size_t)b * Sdim + qrow) * (Sdim / 64);

  // --- probe HW cvt_pk packing order once (wave-uniform, 1 op)
  const bool sw = (cvtpk_raw(0.0f, 1.0f) & 0xFFFFu) != 0u;

  // --- Q fragments (B operand): qf[step] elem i = Q[qrow][step*16+hi*8+i]*QSCL
  bf16x8 qf[4];
  {
    const float* qs = Q + ((size_t)bh * Sdim + qrow) * Ddim;
#pragma unroll
    for (int step = 0; step < 4; ++step) {
      const int d0 = step * 16 + hi * 8;
      float4 a = *(const float4*)(qs + d0);
      float4 c = *(const float4*)(qs + d0 + 4);
      u32x4 f;
      f[0] = cvtpk(a.x * QSCL, a.y * QSCL, sw);
      f[1] = cvtpk(a.z * QSCL, a.w * QSCL, sw);
      f[2] = cvtpk(c.x * QSCL, c.y * QSCL, sw);
      f[3] = cvtpk(c.z * QSCL, c.w * QSCL, sw);
      qf[step] = __builtin_bit_cast(bf16x8, f);
    }
  }

  // --- staging: wave w stages rows [16w,16w+16) of K tile and of V^T tile
  const int srow = 16 * w + (lane >> 3);
  const int sblk = (lane & 7) ^ ((lane >> 3) & 7);  // inverse-swizzled src block
  const int dstw = w * 1024;                        // wave-uniform elem base

#define STAGE(OFFE, kp_, vp_)                                   \
  do {                                                          \
    gll16((kp_), &sm[(OFFE) + dstw]);                           \
    gll16((kp_) + 8 * Ddim, &sm[(OFFE) + dstw + 512]);          \
    gll16((vp_), &sm[(OFFE) + VOFF + dstw]);                    \
    gll16((vp_) + 8 * Sdim, &sm[(OFFE) + VOFF + dstw + 512]);   \
  } while (0)

  f32x16 otA = {0,0,0,0,0,0,0,0,0,0,0,0,0,0,0,0};
  f32x16 otB = {0,0,0,0,0,0,0,0,0,0,0,0,0,0,0,0};
  float lrow = 0.f;

  unsigned long long mwCur = mp[0];
  {
    const __bf16* kp0 = Kbase + (size_t)srow * Ddim + sblk * 8;
    const __bf16* vp0 = Vbase + (size_t)srow * Sdim + sblk * 8;
    STAGE(0, kp0, vp0);
  }
  const __bf16* kpS = Kbase + (size_t)(KVBLK + srow) * Ddim + sblk * 8;
  const __bf16* vpS = Vbase + (size_t)srow * Sdim + KVBLK + sblk * 8;

  // One iteration; RD/ST are compile-time buffer indices, KTN the next kt.
#define ITER(RD, ST, KTN, LAST)                                                \
  do {                                                                         \
    unsigned long long mwNext = 0;                                             \
    if (!(LAST)) {                                                             \
      mwNext = mp[(KTN)];                                                      \
      STAGE((ST) * BUFE, kpS, vpS);                                            \
      kpS += (size_t)KVBLK * Ddim;                                             \
      vpS += KVBLK;                                                            \
      asm volatile("s_waitcnt vmcnt(5)" ::: "memory");                         \
    } else {                                                                   \
      asm volatile("s_waitcnt vmcnt(0)" ::: "memory");                         \
    }                                                                          \
    __builtin_amdgcn_s_barrier();                                              \
    __builtin_amdgcn_sched_barrier(0);                                         \
    f32x16 st0 = {0,0,0,0,0,0,0,0,0,0,0,0,0,0,0,0};                            \
    f32x16 st1 = {0,0,0,0,0,0,0,0,0,0,0,0,0,0,0,0};                            \
    __builtin_amdgcn_s_setprio(1);                                             \
    _Pragma("unroll") for (int step = 0; step < 4; ++step) {                   \
      bf16x8 kf = *(const bf16x8*)&sm[(RD) * BUFE + l31 * 64 +                 \
                                      (((step * 2 + hi) ^ rsw) << 3)];         \
      st0 = __builtin_amdgcn_mfma_f32_32x32x16_bf16(kf, qf[step], st0, 0,0,0); \
    }                                                                          \
    _Pragma("unroll") for (int step = 0; step < 4; ++step) {                   \
      bf16x8 kf = *(const bf16x8*)&sm[(RD) * BUFE + (32 + l31) * 64 +          \
                                      (((step * 2 + hi) ^ rsw) << 3)];         \
      st1 = __builtin_amdgcn_mfma_f32_32x32x16_bf16(kf, qf[step], st1, 0,0,0); \
    }                                                                          \
    __builtin_amdgcn_s_setprio(0);                                             \
    float sv0[16], sv1[16];                                                    \
    const unsigned w0s = ((unsigned)mwCur) >> (hi * 4);                        \
    const unsigned w1s = ((unsigned)(mwCur >> 32)) >> (hi * 4);                \
    _Pragma("unroll") for (int r = 0; r < 16; ++r) {                           \
      const int cr = (r & 3) + 8 * (r >> 2);                                   \
      const float e0 = __builtin_amdgcn_exp2f(st0[r]);                         \
      const float e1 = __builtin_amdgcn_exp2f(st1[r]);                         \
      sv0[r] = ((w0s >> cr) & 1u) ? 0.f : e0;                                  \
      sv1[r] = ((w1s >> cr) & 1u) ? 0.f : e1;                                  \
    }                                                                          \
    float s8[8];                                                               \
    _Pragma("unroll") for (int j = 0; j < 8; ++j)                              \
      s8[j] = (sv0[j] + sv0[j + 8]) + (sv1[j] + sv1[j + 8]);                   \
    lrow += ((s8[0] + s8[4]) + (s8[1] + s8[5])) +                              \
            ((s8[2] + s8[6]) + (s8[3] + s8[7]));                               \
    unsigned pw[16];                                                           \
    if (!sw) packAll<false>(sv0, sv1, pw);                                     \
    else     packAll<true>(sv0, sv1, pw);                                      \
    bf16x8 pb[4];                                                              \
    _Pragma("unroll") for (int ks = 0; ks < 4; ++ks) {                         \
      const unsigned W0 = pw[ks * 4 + 0], W1 = pw[ks * 4 + 1];                 \
      const unsigned X0 = pw[ks * 4 + 2], X1 = pw[ks * 4 + 3];                 \
      const unsigned s1 = hi ? W0 : X0;                                        \
      const unsigned s2 = hi ? W1 : X1;                                        \
      const unsigned r1 = __shfl_xor(s1, 32, 64);                              \
      const unsigned r2 = __shfl_xor(s2, 32, 64);                              \
      u32x4 wv;                                                                \
      wv[0] = hi ? r1 : W0;                                                    \
      wv[1] = hi ? r2 : W1;                                                    \
      wv[2] = hi ? X0 : r1;                                                    \
      wv[3] = hi ? X1 : r2;                                                    \
      pb[ks] = __builtin_bit_cast(bf16x8, wv);                                 \
    }                                                                          \
    __builtin_amdgcn_s_setprio(1);                                             \
    _Pragma("unroll") for (int ks = 0; ks < 4; ++ks) {                         \
      bf16x8 vf = *(const bf16x8*)&sm[(RD) * BUFE + VOFF + l31 * 64 +          \
                                      (((ks * 2 + hi) ^ rsw) << 3)];           \
      otA = __builtin_amdgcn_mfma_f32_32x32x16_bf16(vf, pb[ks], otA, 0,0,0);   \
    }                                                                          \
    _Pragma("unroll") for (int ks = 0; ks < 4; ++ks) {                         \
      bf16x8 vf = *(const bf16x8*)&sm[(RD) * BUFE + VOFF + (32 + l31) * 64 +   \
                                      (((ks * 2 + hi) ^ rsw) << 3)];           \
      otB = __builtin_amdgcn_mfma_f32_32x32x16_bf16(vf, pb[ks], otB, 0,0,0);   \
    }                                                                          \
    __builtin_amdgcn_s_setprio(0);                                             \
    if (!(LAST)) mwCur = mwNext;                                               \
  } while (0)

#pragma unroll 1
  for (int g = 0; g < 7; ++g) {   // kt = 4g .. 4g+3 (0..27)
    ITER(0, 1, 4 * g + 1, false);
    ITER(1, 2, 4 * g + 2, false);
    ITER(2, 3, 4 * g + 3, false);
    ITER(3, 0, 4 * g + 4, false);
  }
  ITER(0, 1, 29, false);   // kt = 28
  ITER(1, 2, 30, false);   // kt = 29
  ITER(2, 3, 31, false);   // kt = 30
  ITER(3, 0, 0, true);     // kt = 31 (no stage, full drain)
#undef ITER
#undef STAGE

  // ---- epilogue: deferred cross-half sum reduce, then O[q][d] = O^T/l
  lrow += __shfl_xor(lrow, 32, 64);
  const float inv = 1.f / (lrow + 1e-30f);
  float* orow = Out + ((size_t)bh * Sdim + qrow) * Ddim;
#pragma unroll
  for (int g = 0; g < 4; ++g) {
    const int d0 = 8 * g + 4 * hi;
    float4 va = {otA[4 * g] * inv, otA[4 * g + 1] * inv,
                 otA[4 * g + 2] * inv, otA[4 * g + 3] * inv};
    float4 vb = {otB[4 * g] * inv, otB[4 * g + 1] * inv,
                 otB[4 * g + 2] * inv, otB[4 * g + 3] * inv};
    *(float4*)(orow + d0) = va;
    *(float4*)(orow + 32 + d0) = vb;
  }
}

// ---------------------------------------------------------------------------
// Fallback (round-1 kernel, known good): no-workspace path
// ---------------------------------------------------------------------------
__global__ __launch_bounds__(256) void attn_fallback(
    const float* __restrict__ Q, const float* __restrict__ K,
    const float* __restrict__ V, const void* __restrict__ maskRaw,
    float* __restrict__ Out) {
  __shared__ alignas(16) __bf16 Kl[KVBLK * Ddim];
  __shared__ alignas(16) __bf16 Vts[Ddim * KVBLK];
  __shared__ alignas(16) __bf16 Pl[4][16 * 64];

  const int tid = threadIdx.x;
  const int lane = tid & 63;
  const int w = tid >> 6;
  const int lhi = lane >> 4;
  const int llo = lane & 15;

  const int qt = blockIdx.x;
  const int bh = blockIdx.y;
  const int b = bh >> 4;
  const int qbase = qt * 64;

  const float* Qp = Q + (size_t)bh * Sdim * Ddim;
  const float* Kp = K + (size_t)bh * Sdim * Ddim;
  const float* Vp = V + (size_t)bh * Sdim * Ddim;

  bool maskBytes = __any(((const unsigned*)maskRaw)[lane] > 1u);

  bf16x8 qf0, qf1;
  {
    const int qr = qbase + w * 16 + llo;
    const float* src = Qp + (size_t)qr * Ddim + lhi * 8;
#pragma unroll
    for (int i = 0; i < 8; ++i) qf0[i] = (__bf16)(src[i] * SCALE);
#pragma unroll
    for (int i = 0; i < 8; ++i) qf1[i] = (__bf16)(src[32 + i] * SCALE);
  }

  f32x4 acc[4] = {{0.f,0.f,0.f,0.f},{0.f,0.f,0.f,0.f},
                  {0.f,0.f,0.f,0.f},{0.f,0.f,0.f,0.f}};
  float mrow[4], lrw[4];
#pragma unroll
  for (int r = 0; r < 4; ++r) { mrow[r] = -3.0e38f; lrw[r] = 0.f; }

  for (int kt = 0; kt < NT; ++kt) {
    __syncthreads();
    {
      int r = tid >> 2;
      int c0 = (tid & 3) << 4;
      const float* ks = Kp + (size_t)(kt * KVBLK + r) * Ddim + c0;
      const float* vs = Vp + (size_t)(kt * KVBLK + r) * Ddim + c0;
      float kv[16], vv[16];
#pragma unroll
      for (int j = 0; j < 4; ++j) {
        *(float4*)(&kv[j * 4]) = *(const float4*)(ks + j * 4);
        *(float4*)(&vv[j * 4]) = *(const float4*)(vs + j * 4);
      }
      const int swzK = (r & 7) << 3;
      bf16x8 k0v, k1v;
#pragma unroll
      for (int j = 0; j < 8; ++j) { k0v[j] = (__bf16)kv[j]; k1v[j] = (__bf16)kv[8 + j]; }
      *(bf16x8*)&Kl[r * 64 + (c0 ^ swzK)] = k0v;
      *(bf16x8*)&Kl[r * 64 + ((c0 + 8) ^ swzK)] = k1v;
#pragma unroll
      for (int j = 0; j < 16; ++j) {
        int d = c0 + j;
        Vts[d * 64 + (r ^ ((d & 7) << 3))] = (__bf16)vv[j];
      }
    }
    __syncthreads();

    float sv[4][4];
#pragma unroll
    for (int cb = 0; cb < 4; ++cb) {
      int krow = cb * 16 + llo;
      int swz = (krow & 7) << 3;
      bf16x8 kf0 = *(const bf16x8*)&Kl[krow * 64 + ((lhi * 8) ^ swz)];
      bf16x8 kf1 = *(const bf16x8*)&Kl[krow * 64 + ((32 + lhi * 8) ^ swz)];
      f32x4 s = {0.f, 0.f, 0.f, 0.f};
      s = __builtin_amdgcn_mfma_f32_16x16x32_bf16(qf0, kf0, s, 0, 0, 0);
      s = __builtin_amdgcn_mfma_f32_16x16x32_bf16(qf1, kf1, s, 0, 0, 0);
#pragma unroll
      for (int r = 0; r < 4; ++r) {
        size_t q = qbase + w * 16 + lhi * 4 + r;
        size_t k = (size_t)kt * KVBLK + cb * 16 + llo;
        size_t idx = ((size_t)b * Sdim + q) * Sdim + k;
        bool masked = maskBytes ? (((const unsigned char*)maskRaw)[idx] != 0)
                                : (((const int*)maskRaw)[idx] != 0);
        sv[cb][r] = masked ? -1e9f : s[r];
      }
    }

    float corr[4], tsum[4];
#pragma unroll
    for (int r = 0; r < 4; ++r) {
      float mx = fmaxf(fmaxf(sv[0][r], sv[1][r]), fmaxf(sv[2][r], sv[3][r]));
#pragma unroll
      for (int off = 1; off < 16; off <<= 1)
        mx = fmaxf(mx, __shfl_xor(mx, off, 64));
      float mnew = fmaxf(mrow[r], mx);
      corr[r] = __expf(mrow[r] - mnew);
      mrow[r] = mnew;
      tsum[r] = 0.f;
    }
#pragma unroll
    for (int cb = 0; cb < 4; ++cb) {
#pragma unroll
      for (int r = 0; r < 4; ++r) {
        float p = __expf(sv[cb][r] - mrow[r]);
        tsum[r] += p;
        int row = lhi * 4 + r;
        int col = cb * 16 + llo;
        Pl[w][row * 64 + (col ^ ((row & 7) << 3))] = (__bf16)p;
      }
    }
#pragma unroll
    for (int r = 0; r < 4; ++r) {
      float s = tsum[r];
#pragma unroll
      for (int off = 1; off < 16; off <<= 1)
        s += __shfl_xor(s, off, 64);
      lrw[r] = lrw[r] * corr[r] + s;
#pragma unroll
      for (int db = 0; db < 4; ++db) acc[db][r] *= corr[r];
    }
    asm volatile("s_waitcnt lgkmcnt(0)" ::: "memory");

    bf16x8 pf0 = *(const bf16x8*)&Pl[w][llo * 64 + ((lhi * 8) ^ ((llo & 7) << 3))];
    bf16x8 pf1 = *(const bf16x8*)&Pl[w][llo * 64 + ((32 + lhi * 8) ^ ((llo & 7) << 3))];
#pragma unroll
    for (int db = 0; db < 4; ++db) {
      int d = db * 16 + llo;
      int swz = (d & 7) << 3;
      bf16x8 vf0 = *(const bf16x8*)&Vts[d * 64 + ((lhi * 8) ^ swz)];
      bf16x8 vf1 = *(const bf16x8*)&Vts[d * 64 + ((32 + lhi * 8) ^ swz)];
      acc[db] = __builtin_amdgcn_mfma_f32_16x16x32_bf16(pf0, vf0, acc[db], 0, 0, 0);
      acc[db] = __builtin_amdgcn_mfma_f32_16x16x32_bf16(pf1, vf1, acc[db], 0, 0, 0);
    }
  }

#pragma unroll
  for (int r = 0; r < 4; ++r) {
    float inv = 1.f / lrw[r];
    int q = qbase + w * 16 + lhi * 4 + r;
    float* dst = Out + ((size_t)bh * Sdim + q) * Ddim + llo;
#pragma unroll
    for (int db = 0; db < 4; ++db) dst[db * 16] = acc[db][r] * inv;
  }
}

extern "C" void kernel_launch(void* const* d_in, const int* in_sizes, int n_in,
                              void* d_out, int out_size, void* d_ws, size_t ws_size,
                              hipStream_t stream) {
  const float* Q = (const float*)d_in[0];
  const float* K = (const float*)d_in[1];
  const float* V = (const float*)d_in[2];
  const void* mask = d_in[3];
  float* out = (float*)d_out;

  const size_t packed_bytes =
      (size_t)Bdim * Sdim * (Sdim / 64) * sizeof(unsigned long long);   // 1 MiB
  const size_t tensor_bf16 = (size_t)Bdim * Hdim * Sdim * Ddim * 2;     // 8 MiB

  if (ws_size >= packed_bytes + 2 * tensor_bf16) {
    unsigned long long* packed = (unsigned long long*)d_ws;
    __bf16* Kb = (__bf16*)((char*)d_ws + packed_bytes);
    __bf16* Vt = (__bf16*)((char*)d_ws + packed_bytes + tensor_bf16);
    prep_all<<<512 + Bdim * Hdim * (Sdim / 64), 256, 0, stream>>>(
        mask, packed, K, V, Kb, Vt);
    attn5<<<(Sdim / QTILE) * Bdim * Hdim, 256, 0, stream>>>(Q, Kb, Vt, packed, out);
  } else {
    attn_fallback<<<dim3(Sdim / 64, Bdim * Hdim), 256, 0, stream>>>(Q, K, V, mask, out);
  }
}